// Round 1
// baseline (371.806 us; speedup 1.0000x reference)
//
#include <hip/hip_runtime.h>

// Sub4BitLinear: y[b,s,o] = sum_i x[b,s,i] * grid[o, codes[o,i]]
// == C[M,N] = X[M,K] @ W[N,K]^T  with M=8192, N=4096, K=4096
// Pipeline: (1) x f32->bf16, (2) dequant codes->bf16 W, (3) bf16 MFMA GEMM.

#define M_DIM 8192
#define N_DIM 4096
#define K_DIM 4096

typedef __attribute__((ext_vector_type(8))) short short8;
typedef __attribute__((ext_vector_type(4))) float f32x4;

#define AS1 __attribute__((address_space(1)))
#define AS3 __attribute__((address_space(3)))

__device__ __forceinline__ unsigned short f2bf(float f) {
    unsigned int u = __builtin_bit_cast(unsigned int, f);
    u += 0x7fffu + ((u >> 16) & 1u);   // round-to-nearest-even
    return (unsigned short)(u >> 16);
}

__device__ __forceinline__ void gl_lds16(const void* g, void* l) {
    __builtin_amdgcn_global_load_lds((const AS1 void*)g, (AS3 void*)l, 16, 0, 0);
}

// ---------------- kernel 1: x f32 -> bf16 ----------------
__global__ __launch_bounds__(256) void cvt_x(const float4* __restrict__ X,
                                             ushort4* __restrict__ O, int n4) {
    int stride = gridDim.x * blockDim.x;
    for (int i = blockIdx.x * blockDim.x + threadIdx.x; i < n4; i += stride) {
        float4 v = X[i];
        ushort4 o;
        o.x = f2bf(v.x); o.y = f2bf(v.y); o.z = f2bf(v.z); o.w = f2bf(v.w);
        O[i] = o;
    }
}

// ---------------- kernel 2: dequant W (one block per output row) ----------------
__global__ __launch_bounds__(256) void dequant(const int* __restrict__ CD,
                                               const float* __restrict__ G,
                                               ushort* __restrict__ W) {
    const int o = blockIdx.x;
    __shared__ ushort gs[8];
    if (threadIdx.x < 8) gs[threadIdx.x] = f2bf(G[o * 8 + threadIdx.x]);
    __syncthreads();
    const int4* cp = (const int4*)(CD + (size_t)o * K_DIM);
    ushort4* wp = (ushort4*)(W + (size_t)o * K_DIM);
#pragma unroll
    for (int r = 0; r < 4; ++r) {
        int idx = r * 256 + threadIdx.x;      // 1024 int4 per row
        int4 c = cp[idx];
        ushort4 w;
        w.x = gs[c.x]; w.y = gs[c.y]; w.z = gs[c.z]; w.w = gs[c.w];
        wp[idx] = w;
    }
}

// ---------------- kernel 3: bf16 MFMA GEMM, C = A[M,K] * B[N,K]^T ----------------
// 128x128 tile, BK=32, 4 waves (2x2), each wave 64x64 via 4x4 frags of 16x16x32.
__global__ __launch_bounds__(256, 2) void gemm_bt(const ushort* __restrict__ A,
                                                  const ushort* __restrict__ B,
                                                  float* __restrict__ C) {
    __shared__ ushort As[2][128 * 32];
    __shared__ ushort Bs[2][128 * 32];

    const int tid = threadIdx.x;
    const int lane = tid & 63;
    const int w = tid >> 6;                 // wave 0..3

    // XCD-aware bijective swizzle (nwg = 2048, divisible by 8)
    const int nwg = gridDim.x;
    int wg = blockIdx.x;
    const int cpx = nwg >> 3;
    wg = (wg & 7) * cpx + (wg >> 3);
    const int ntn = N_DIM >> 7;             // tiles along N
    const int bm = (wg / ntn) << 7;
    const int bn = (wg % ntn) << 7;

    // staging: wave w covers tile rows [w*32, w*32+32), 2 instrs x 16 rows
    const int srow = lane >> 2;             // 0..15
    const int scol = (lane & 3) << 3;       // 0,8,16,24 (bf16 units)
    const ushort* gA0 = A + (size_t)(bm + w * 32 + srow) * K_DIM + scol;
    const ushort* gA1 = gA0 + (size_t)16 * K_DIM;
    const ushort* gB0 = B + (size_t)(bn + w * 32 + srow) * K_DIM + scol;
    const ushort* gB1 = gB0 + (size_t)16 * K_DIM;

    const int wr = w >> 1, wc = w & 1;      // wave's 64x64 quadrant
    const int fr = lane & 15;               // frag row
    const int fk = (lane >> 4) << 3;        // frag k offset: 0/8/16/24

    f32x4 acc[4][4] = {};

#define STAGE(buf, kt)                                                  \
    {                                                                   \
        const int ko = (kt) << 5;                                       \
        gl_lds16(gA0 + ko, &As[buf][(w * 32) * 32]);                    \
        gl_lds16(gA1 + ko, &As[buf][(w * 32 + 16) * 32]);               \
        gl_lds16(gB0 + ko, &Bs[buf][(w * 32) * 32]);                    \
        gl_lds16(gB1 + ko, &Bs[buf][(w * 32 + 16) * 32]);               \
    }

    const int NK = K_DIM >> 5;              // 128 K-steps
    STAGE(0, 0);
    __syncthreads();
    int cur = 0;
    for (int kt = 0; kt < NK; ++kt) {
        if (kt + 1 < NK) STAGE(cur ^ 1, kt + 1);
        short8 af[4], bf[4];
#pragma unroll
        for (int i = 0; i < 4; ++i) {
            af[i] = *(const short8*)&As[cur][(wr * 64 + i * 16 + fr) * 32 + fk];
            bf[i] = *(const short8*)&Bs[cur][(wc * 64 + i * 16 + fr) * 32 + fk];
        }
#pragma unroll
        for (int i = 0; i < 4; ++i)
#pragma unroll
            for (int j = 0; j < 4; ++j)
                acc[i][j] = __builtin_amdgcn_mfma_f32_16x16x32_bf16(af[i], bf[j], acc[i][j], 0, 0, 0);
        __syncthreads();
        cur ^= 1;
    }
#undef STAGE

    // C/D layout: col = lane&15, row = (lane>>4)*4 + reg
#pragma unroll
    for (int i = 0; i < 4; ++i) {
        const int row0 = bm + wr * 64 + i * 16 + ((lane >> 4) << 2);
#pragma unroll
        for (int j = 0; j < 4; ++j) {
            const int col = bn + wc * 64 + j * 16 + (lane & 15);
#pragma unroll
            for (int r = 0; r < 4; ++r)
                C[(size_t)(row0 + r) * N_DIM + col] = acc[i][j][r];
        }
    }
}

// ---------------- fallback: tiled f32 GEMM with on-the-fly dequant ----------------
__global__ __launch_bounds__(256) void fb_gemm(const float* __restrict__ X,
                                               const float* __restrict__ G,
                                               const int* __restrict__ CD,
                                               float* __restrict__ Y) {
    __shared__ float xs[16][64];
    __shared__ float ws[16][64];
    const int bm = blockIdx.y << 6, bn = blockIdx.x << 6;
    const int tid = threadIdx.x;
    const int tn = tid & 15, tm = tid >> 4;
    float acc[4][4] = {};
    for (int k0 = 0; k0 < K_DIM; k0 += 16) {
#pragma unroll
        for (int r = 0; r < 4; ++r) {
            int e = r * 256 + tid;
            int mm = e >> 4, kk = e & 15;
            xs[kk][mm] = X[(size_t)(bm + mm) * K_DIM + k0 + kk];
            int code = CD[(size_t)(bn + mm) * K_DIM + k0 + kk];
            ws[kk][mm] = G[(bn + mm) * 8 + code];
        }
        __syncthreads();
#pragma unroll
        for (int kk = 0; kk < 16; ++kk)
#pragma unroll
            for (int i = 0; i < 4; ++i)
#pragma unroll
                for (int j = 0; j < 4; ++j)
                    acc[i][j] += xs[kk][tm * 4 + i] * ws[kk][tn * 4 + j];
        __syncthreads();
    }
#pragma unroll
    for (int i = 0; i < 4; ++i)
#pragma unroll
        for (int j = 0; j < 4; ++j)
            Y[(size_t)(bm + tm * 4 + i) * N_DIM + bn + tn * 4 + j] = acc[i][j];
}

extern "C" void kernel_launch(void* const* d_in, const int* in_sizes, int n_in,
                              void* d_out, int out_size, void* d_ws, size_t ws_size,
                              hipStream_t stream) {
    const float* x = (const float*)d_in[0];
    const float* qg = (const float*)d_in[1];
    const int* wc = (const int*)d_in[2];
    float* y = (float*)d_out;

    const size_t xb_elems = (size_t)M_DIM * K_DIM;
    const size_t wb_elems = (size_t)N_DIM * K_DIM;
    const size_t need = (xb_elems + wb_elems) * sizeof(ushort);

    if (ws_size >= need) {
        ushort* xb = (ushort*)d_ws;
        ushort* wb = xb + xb_elems;
        const int n4 = (int)(xb_elems / 4);
        hipLaunchKernelGGL(cvt_x, dim3(2048), dim3(256), 0, stream,
                           (const float4*)x, (ushort4*)xb, n4);
        hipLaunchKernelGGL(dequant, dim3(N_DIM), dim3(256), 0, stream, wc, qg, wb);
        const int nwg = (M_DIM / 128) * (N_DIM / 128);   // 2048
        hipLaunchKernelGGL(gemm_bt, dim3(nwg), dim3(256), 0, stream, xb, wb, y);
    } else {
        hipLaunchKernelGGL(fb_gemm, dim3(N_DIM / 64, M_DIM / 64), dim3(256), 0, stream,
                           x, qg, wc, y);
    }
}